// Round 2
// baseline (671.565 us; speedup 1.0000x reference)
//
#include <hip/hip_runtime.h>

typedef _Float16 half8  __attribute__((ext_vector_type(8)));
typedef _Float16 half2v __attribute__((ext_vector_type(2)));
typedef float    floatx4 __attribute__((ext_vector_type(4)));
typedef float    f4v     __attribute__((ext_vector_type(4)));

#define NND 8192
#define PA  40   // LDS pitch in f16 (80 B: 16B-aligned rows, swizzle kills conflicts)

__device__ __forceinline__ int swzk(int m, int k) { return k ^ (((m >> 3) & 3) << 3); }

// ---------------- deg[j] = sum_i relu(attn[i,j]) ----------------
__global__ __launch_bounds__(256) void k_deg(const float* __restrict__ A, float* __restrict__ deg) {
    int j4 = blockIdx.x * 256 + threadIdx.x;                    // float4 column index, 0..2047
    const f4v* Ap = (const f4v*)A + (size_t)blockIdx.y * 128 * 2048 + j4;
    f4v s = {0.f, 0.f, 0.f, 0.f};
    #pragma unroll 4
    for (int i = 0; i < 128; ++i) {
        f4v v = Ap[(size_t)i * 2048];
        s[0] += fmaxf(v[0], 0.f); s[1] += fmaxf(v[1], 0.f);
        s[2] += fmaxf(v[2], 0.f); s[3] += fmaxf(v[3], 0.f);
    }
    #pragma unroll
    for (int c = 0; c < 4; ++c) atomicAdd(&deg[4 * j4 + c], s[c]);
}

__global__ __launch_bounds__(256) void k_dis(const float* __restrict__ deg, float* __restrict__ dis) {
    int j = blockIdx.x * 256 + threadIdx.x;
    float d = deg[j];
    dis[j] = d > 0.f ? 1.f / sqrtf(d) : 0.f;
}

// ------------- small GEMM: outT[n][i] = f16( dis[i] * (A@B)[i,n] * out_scale ) -------------
// A: [8192 x 256] row-major (fp32 with optional row-gather + x16 scale, or f16).
// B: [256 x NB] fp32 row-major. Tile 128m x 64n x 32k, 4 waves of 64x32.
template <typename AT>
__global__ __launch_bounds__(256) void k_mm_small(
    const AT* __restrict__ Abase, const int* __restrict__ gather,
    const float* __restrict__ B, int NB,
    _Float16* __restrict__ outT, const float* __restrict__ dis, float out_scale) {

    __shared__ _Float16 As[128 * PA];
    __shared__ _Float16 Bs[64 * PA];

    int t  = threadIdx.x;
    int i0 = blockIdx.x * 128;
    int n0 = blockIdx.y * 64;

    int am = t & 127, akh = t >> 7;      // A-stage: row, k-half
    int row = i0 + am;
    if (gather) row = gather[row];
    const AT* arow = Abase + (size_t)row * 256;

    int tp = t & 15, kp = t >> 4;        // B-stage: n-group, k-pair

    int lane = t & 63, w = t >> 6;
    int wm = w & 1, wn = w >> 1;
    int lm = lane & 15, q = lane >> 4;

    floatx4 acc[4][2];
    #pragma unroll
    for (int a = 0; a < 4; ++a)
        #pragma unroll
        for (int b = 0; b < 2; ++b) acc[a][b] = (floatx4){0.f, 0.f, 0.f, 0.f};

    for (int ks = 0; ks < 8; ++ks) {
        int c0 = ks * 32;

        half8 av[2];
        if constexpr (sizeof(AT) == 4) {
            #pragma unroll
            for (int cc = 0; cc < 2; ++cc) {
                f4v v0 = *(const f4v*)(arow + c0 + akh * 16 + cc * 8);
                f4v v1 = *(const f4v*)(arow + c0 + akh * 16 + cc * 8 + 4);
                half8 hv;
                #pragma unroll
                for (int e = 0; e < 4; ++e) {
                    hv[e]     = (_Float16)(16.f * v0[e]);   // x scaled by 16 (f16 subnormal safety)
                    hv[4 + e] = (_Float16)(16.f * v1[e]);
                }
                av[cc] = hv;
            }
        } else {
            av[0] = *(const half8*)(arow + c0 + akh * 16);
            av[1] = *(const half8*)(arow + c0 + akh * 16 + 8);
        }

        const float* bp = B + (size_t)(c0 + 2 * kp) * NB + n0 + 4 * tp;
        f4v r0 = *(const f4v*)bp;
        f4v r1 = *(const f4v*)(bp + NB);

        __syncthreads();
        #pragma unroll
        for (int cc = 0; cc < 2; ++cc) {
            int k = akh * 16 + cc * 8;
            *(half8*)(&As[am * PA + swzk(am, k)]) = av[cc];
        }
        #pragma unroll
        for (int u = 0; u < 4; ++u) {
            int n = 4 * tp + u;
            half2v p = {(_Float16)r0[u], (_Float16)r1[u]};
            *(half2v*)(&Bs[n * PA + swzk(n, 2 * kp)]) = p;
        }
        __syncthreads();

        half8 af[4], bf[2];
        #pragma unroll
        for (int mt = 0; mt < 4; ++mt) {
            int m = wm * 64 + mt * 16 + lm;
            af[mt] = *(const half8*)(&As[m * PA + swzk(m, q * 8)]);
        }
        #pragma unroll
        for (int nt = 0; nt < 2; ++nt) {
            int n = wn * 32 + nt * 16 + lm;
            bf[nt] = *(const half8*)(&Bs[n * PA + swzk(n, q * 8)]);
        }
        #pragma unroll
        for (int mt = 0; mt < 4; ++mt)
            #pragma unroll
            for (int nt = 0; nt < 2; ++nt)
                acc[mt][nt] = __builtin_amdgcn_mfma_f32_16x16x32_f16(af[mt], bf[nt], acc[mt][nt], 0, 0, 0);
    }

    #pragma unroll
    for (int mt = 0; mt < 4; ++mt) {
        int ib = i0 + wm * 64 + mt * 16 + q * 4;
        #pragma unroll
        for (int nt = 0; nt < 2; ++nt) {
            int n = n0 + wn * 32 + nt * 16 + lm;
            #pragma unroll
            for (int r = 0; r < 4; ++r) {
                float v = acc[mt][nt][r] * dis[ib + r] * out_scale;
                outT[(size_t)n * NND + ib + r] = (_Float16)v;   // stored pre-transposed [n][i]
            }
        }
    }
}

// ------------- big GEMM: C[j][n] += sum_i f16(relu(W[i,j])) * Bt[n][i]  (split-K atomic) -------------
// W: attn fp32 [8192 x 8192]; Bt: f16 [BN x 8192] (pre-transposed). Tile 128m x BN x 32k.
// NOTE: the edge weight is relu(attn) — relu MUST be applied here, not only in k_deg.
template <int BN>   // 256 (layer 1) or 128 (layer 2)
__global__ __launch_bounds__(256, 2) void k_mm_big(
    const float* __restrict__ W, const _Float16* __restrict__ Bt, float* __restrict__ C) {

    constexpr int NT  = BN / 32;             // n-tiles per wave
    constexpr int NBV = (BN == 256) ? 4 : 2;
    __shared__ _Float16 As[128 * PA];
    __shared__ _Float16 Bs[BN * PA];

    int t = threadIdx.x;
    int j0 = blockIdx.x * 128;
    int i_begin = blockIdx.z * 1024;

    int tp = t & 15, kp = t >> 4;

    int lane = t & 63, w = t >> 6;
    int wm = w & 1, wn = w >> 1;
    int lm = lane & 15, q = lane >> 4;

    floatx4 acc[4][NT];
    #pragma unroll
    for (int a = 0; a < 4; ++a)
        #pragma unroll
        for (int b = 0; b < NT; ++b) acc[a][b] = (floatx4){0.f, 0.f, 0.f, 0.f};

    for (int ks = 0; ks < 32; ++ks) {
        int ib = i_begin + ks * 32;

        // A loads: W rows 2kp,2kp+1, cols j0+tp+16u  (transpose staging, relu applied)
        const float* r0 = W + (size_t)(ib + 2 * kp) * NND + j0 + tp;
        float fa[8], fb[8];
        #pragma unroll
        for (int u = 0; u < 8; ++u) {
            fa[u] = fmaxf(r0[16 * u], 0.f);
            fb[u] = fmaxf(r0[NND + 16 * u], 0.f);
        }

        half8 bv[NBV];
        if constexpr (BN == 256) {
            const _Float16* src = Bt + (size_t)t * NND + ib;
            #pragma unroll
            for (int c = 0; c < 4; ++c) bv[c] = *(const half8*)(src + 8 * c);
        } else {
            int n = t & 127, kh = t >> 7;
            const _Float16* src = Bt + (size_t)n * NND + ib + 16 * kh;
            #pragma unroll
            for (int c = 0; c < 2; ++c) bv[c] = *(const half8*)(src + 8 * c);
        }

        __syncthreads();
        #pragma unroll
        for (int u = 0; u < 8; ++u) {
            int m = tp + 16 * u;
            half2v p = {(_Float16)fa[u], (_Float16)fb[u]};
            *(half2v*)(&As[m * PA + swzk(m, 2 * kp)]) = p;
        }
        if constexpr (BN == 256) {
            #pragma unroll
            for (int c = 0; c < 4; ++c)
                *(half8*)(&Bs[t * PA + swzk(t, 8 * c)]) = bv[c];
        } else {
            int n = t & 127, kh = t >> 7;
            #pragma unroll
            for (int c = 0; c < 2; ++c) {
                int k = 16 * kh + 8 * c;
                *(half8*)(&Bs[n * PA + swzk(n, k)]) = bv[c];
            }
        }
        __syncthreads();

        half8 af[4], bf[NT];
        #pragma unroll
        for (int mt = 0; mt < 4; ++mt) {
            int m = wm * 64 + mt * 16 + lm;
            af[mt] = *(const half8*)(&As[m * PA + swzk(m, q * 8)]);
        }
        #pragma unroll
        for (int nt = 0; nt < NT; ++nt) {
            int n = wn * (BN / 2) + nt * 16 + lm;
            bf[nt] = *(const half8*)(&Bs[n * PA + swzk(n, q * 8)]);
        }
        #pragma unroll
        for (int mt = 0; mt < 4; ++mt)
            #pragma unroll
            for (int nt = 0; nt < NT; ++nt)
                acc[mt][nt] = __builtin_amdgcn_mfma_f32_16x16x32_f16(af[mt], bf[nt], acc[mt][nt], 0, 0, 0);
    }

    #pragma unroll
    for (int mt = 0; mt < 4; ++mt) {
        int rb = j0 + wm * 64 + mt * 16 + q * 4;
        #pragma unroll
        for (int nt = 0; nt < NT; ++nt) {
            int col = wn * (BN / 2) + nt * 16 + lm;
            #pragma unroll
            for (int r = 0; r < 4; ++r)
                atomicAdd(&C[(size_t)(rb + r) * BN + col], acc[mt][nt][r]);
        }
    }
}

// ------------- epilogue: out = f16( (dis[j]*C/1024 + bias[n]) [relu] * 64 ) -------------
template <int NSH, bool RELU>
__global__ __launch_bounds__(256) void k_finalize(const float* __restrict__ C, const float* __restrict__ dis,
                                                  const float* __restrict__ bias, _Float16* __restrict__ out) {
    int idx = blockIdx.x * 256 + threadIdx.x;
    int j = idx >> NSH;
    int n = idx & ((1 << NSH) - 1);
    float v = C[idx] * (1.f / 1024.f) * dis[j] + bias[n];
    if (RELU) v = fmaxf(v, 0.f);
    out[idx] = (_Float16)(v * 64.f);
}

// ------------- edge scores: 16 lanes per edge, zh rows are 256B -------------
__global__ __launch_bounds__(256) void k_edges(const _Float16* __restrict__ zh, const int* __restrict__ ei,
                                               float* __restrict__ out, int npred) {
    int g = (blockIdx.x * 256 + threadIdx.x) >> 4;
    int l = threadIdx.x & 15;
    if (g >= npred) return;
    int a = ei[g], b = ei[npred + g];
    half8 za = *(const half8*)(zh + (size_t)a * 128 + l * 8);
    half8 zb = *(const half8*)(zh + (size_t)b * 128 + l * 8);
    float s = 0.f;
    #pragma unroll
    for (int e = 0; e < 8; ++e) s += (float)za[e] * (float)zb[e];
    s += __shfl_xor(s, 1);
    s += __shfl_xor(s, 2);
    s += __shfl_xor(s, 4);
    s += __shfl_xor(s, 8);
    if (l == 0) out[g] = s * (1.f / 4096.f);   // undo the 64x on each z
}

extern "C" void kernel_launch(void* const* d_in, const int* in_sizes, int n_in,
                              void* d_out, int out_size, void* d_ws, size_t ws_size,
                              hipStream_t stream) {
    const int*   nodes = (const int*)d_in[0];
    const float* attn  = (const float*)d_in[1];
    const int*   eidx  = (const int*)d_in[2];
    const float* emb   = (const float*)d_in[3];
    const float* W1    = (const float*)d_in[4];
    const float* b1    = (const float*)d_in[5];
    const float* W2    = (const float*)d_in[6];
    const float* b2    = (const float*)d_in[7];
    float* out = (float*)d_out;
    int npred = in_sizes[2] / 2;

    char* ws = (char*)d_ws;
    float*    deg = (float*)(ws);                       // 32 KB
    float*    dis = (float*)(ws + 0x8000);              // 32 KB
    float*    C1  = (float*)(ws + 0x10000);             // 8 MB  fp32 [8192][256]
    float*    C2  = (float*)(ws + 0x810000);            // 4 MB  fp32 [8192][128]
    _Float16* M1p = (_Float16*)(ws + 0xC10000);         // 4 MB  f16 [256][8192]
    _Float16* h   = (_Float16*)(ws + 0x1010000);        // 4 MB  f16 [8192][256]
    _Float16* M2p = (_Float16*)(ws + 0x1410000);        // 2 MB  f16 [128][8192]
    _Float16* zh  = (_Float16*)(ws + 0x1610000);        // 2 MB  f16 [8192][128]

    hipMemsetAsync(deg, 0, 8192 * sizeof(float), stream);
    hipMemsetAsync(C1, 0, (size_t)8192 * 256 * sizeof(float), stream);
    hipMemsetAsync(C2, 0, (size_t)8192 * 128 * sizeof(float), stream);

    k_deg<<<dim3(8, 64), 256, 0, stream>>>(attn, deg);
    k_dis<<<32, 256, 0, stream>>>(deg, dis);

    // M1p[n][i] = f16(1024 * dis_i * (x@W1)[i,n]);  A staged as 16*x, so out_scale = 64
    k_mm_small<float><<<dim3(64, 4), 256, 0, stream>>>(emb, nodes, W1, 256, M1p, dis, 64.f);
    k_mm_big<256><<<dim3(64, 1, 8), 256, 0, stream>>>(attn, M1p, C1);
    // h = relu(dis_j*C1/1024 + b1) * 64
    k_finalize<8, true><<<8192, 256, 0, stream>>>(C1, dis, b1, h);
    // M2p[n][i] = f16(1024 * dis_i * M2t[i,n]); C = 64*M2t, so out_scale = 16
    k_mm_small<_Float16><<<dim3(64, 2), 256, 0, stream>>>(h, nullptr, W2, 128, M2p, dis, 16.f);
    k_mm_big<128><<<dim3(64, 1, 8), 256, 0, stream>>>(attn, M2p, C2);
    // zh = (dis_j*C2/1024 + b2) * 64
    k_finalize<7, false><<<4096, 256, 0, stream>>>(C2, dis, b2, zh);

    k_edges<<<(npred + 15) / 16, 256, 0, stream>>>(zh, eidx, out, npred);
}

// Round 3
// 645.127 us; speedup vs baseline: 1.0410x; 1.0410x over previous
//
#include <hip/hip_runtime.h>

typedef _Float16 half8  __attribute__((ext_vector_type(8)));
typedef _Float16 half4v __attribute__((ext_vector_type(4)));
typedef _Float16 half2v __attribute__((ext_vector_type(2)));
typedef float    floatx4 __attribute__((ext_vector_type(4)));
typedef float    f4v     __attribute__((ext_vector_type(4)));

#define NND 8192
#define PA  40   // LDS pitch (f16) for GEMM tiles
#define PT  136  // LDS pitch (f16) for transpose tile (16B-aligned rows)

__device__ __forceinline__ int swzk(int m, int k) { return k ^ (((m >> 3) & 3) << 3); }

// ---- fused: deg[j] += sum_i relu(attn[i,j]);  Wh[j][i] = f16(relu(attn[i,j])) ----
// 128x128 tile; read coalesced along j, transpose in LDS, write coalesced along i.
__global__ __launch_bounds__(256) void k_degT(const float* __restrict__ A,
                                              _Float16* __restrict__ Wh,
                                              float* __restrict__ deg) {
    __shared__ _Float16 T[128 * PT];
    __shared__ float sdeg[8 * 128];
    int t  = threadIdx.x;
    int j0 = blockIdx.x * 128, i0 = blockIdx.y * 128;
    int c = t & 31;      // j4-group: cols j0 + 4c .. 4c+3
    int g = t >> 5;      // 0..7: row group

    f4v s = {0.f, 0.f, 0.f, 0.f};
    #pragma unroll
    for (int p = 0; p < 2; ++p) {                       // 2 passes x 64 rows
        int rb = 64 * p + 8 * g;                        // 8 consecutive rows per thread
        f4v v[8];
        #pragma unroll
        for (int rr = 0; rr < 8; ++rr)
            v[rr] = *(const f4v*)(A + (size_t)(i0 + rb + rr) * NND + j0 + 4 * c);
        #pragma unroll
        for (int rr = 0; rr < 8; ++rr)
            #pragma unroll
            for (int u = 0; u < 4; ++u) v[rr][u] = fmaxf(v[rr][u], 0.f);
        #pragma unroll
        for (int u = 0; u < 4; ++u) {
            half8 hv;
            #pragma unroll
            for (int rr = 0; rr < 8; ++rr) { hv[rr] = (_Float16)v[rr][u]; s[u] += v[rr][u]; }
            *(half8*)(&T[(4 * c + u) * PT + rb]) = hv;  // transposed: row=j, col=i
        }
    }
    *(f4v*)(&sdeg[g * 128 + 4 * c]) = s;
    __syncthreads();

    if (t < 128) {
        float d = 0.f;
        #pragma unroll
        for (int g2 = 0; g2 < 8; ++g2) d += sdeg[g2 * 128 + t];
        atomicAdd(&deg[j0 + t], d);
    }

    #pragma unroll
    for (int p = 0; p < 8; ++p) {                       // write phase: coalesced along i
        int j  = 16 * p + (t >> 4);
        int ic = (t & 15) * 8;
        half8 hv = *(const half8*)(&T[j * PT + ic]);
        *(half8*)(Wh + (size_t)(j0 + j) * NND + i0 + ic) = hv;
    }
}

__global__ __launch_bounds__(256) void k_dis(const float* __restrict__ deg, float* __restrict__ dis) {
    int j = blockIdx.x * 256 + threadIdx.x;
    float d = deg[j];
    dis[j] = d > 0.f ? 1.f / sqrtf(d) : 0.f;
}

// ------------- small GEMM: outT[n][i] = f16( dis[i] * (A@B)[i,n] * out_scale ) -------------
template <typename AT>
__global__ __launch_bounds__(256) void k_mm_small(
    const AT* __restrict__ Abase, const int* __restrict__ gather,
    const float* __restrict__ B, int NB,
    _Float16* __restrict__ outT, const float* __restrict__ dis, float out_scale) {

    __shared__ _Float16 As[128 * PA];
    __shared__ _Float16 Bs[64 * PA];

    int t  = threadIdx.x;
    int i0 = blockIdx.x * 128;
    int n0 = blockIdx.y * 64;

    int am = t & 127, akh = t >> 7;
    int row = i0 + am;
    if (gather) row = gather[row];
    const AT* arow = Abase + (size_t)row * 256;

    int tp = t & 15, kp = t >> 4;

    int lane = t & 63, w = t >> 6;
    int wm = w & 1, wn = w >> 1;
    int lm = lane & 15, q = lane >> 4;

    floatx4 acc[4][2];
    #pragma unroll
    for (int a = 0; a < 4; ++a)
        #pragma unroll
        for (int b = 0; b < 2; ++b) acc[a][b] = (floatx4){0.f, 0.f, 0.f, 0.f};

    for (int ks = 0; ks < 8; ++ks) {
        int c0 = ks * 32;

        half8 av[2];
        if constexpr (sizeof(AT) == 4) {
            #pragma unroll
            for (int cc = 0; cc < 2; ++cc) {
                f4v v0 = *(const f4v*)(arow + c0 + akh * 16 + cc * 8);
                f4v v1 = *(const f4v*)(arow + c0 + akh * 16 + cc * 8 + 4);
                half8 hv;
                #pragma unroll
                for (int e = 0; e < 4; ++e) {
                    hv[e]     = (_Float16)(16.f * v0[e]);
                    hv[4 + e] = (_Float16)(16.f * v1[e]);
                }
                av[cc] = hv;
            }
        } else {
            av[0] = *(const half8*)(arow + c0 + akh * 16);
            av[1] = *(const half8*)(arow + c0 + akh * 16 + 8);
        }

        const float* bp = B + (size_t)(c0 + 2 * kp) * NB + n0 + 4 * tp;
        f4v r0 = *(const f4v*)bp;
        f4v r1 = *(const f4v*)(bp + NB);

        __syncthreads();
        #pragma unroll
        for (int cc = 0; cc < 2; ++cc) {
            int k = akh * 16 + cc * 8;
            *(half8*)(&As[am * PA + swzk(am, k)]) = av[cc];
        }
        #pragma unroll
        for (int u = 0; u < 4; ++u) {
            int n = 4 * tp + u;
            half2v p = {(_Float16)r0[u], (_Float16)r1[u]};
            *(half2v*)(&Bs[n * PA + swzk(n, 2 * kp)]) = p;
        }
        __syncthreads();

        half8 af[4], bf[2];
        #pragma unroll
        for (int mt = 0; mt < 4; ++mt) {
            int m = wm * 64 + mt * 16 + lm;
            af[mt] = *(const half8*)(&As[m * PA + swzk(m, q * 8)]);
        }
        #pragma unroll
        for (int nt = 0; nt < 2; ++nt) {
            int n = wn * 32 + nt * 16 + lm;
            bf[nt] = *(const half8*)(&Bs[n * PA + swzk(n, q * 8)]);
        }
        #pragma unroll
        for (int mt = 0; mt < 4; ++mt)
            #pragma unroll
            for (int nt = 0; nt < 2; ++nt)
                acc[mt][nt] = __builtin_amdgcn_mfma_f32_16x16x32_f16(af[mt], bf[nt], acc[mt][nt], 0, 0, 0);
    }

    #pragma unroll
    for (int mt = 0; mt < 4; ++mt) {
        int ib = i0 + wm * 64 + mt * 16 + q * 4;
        #pragma unroll
        for (int nt = 0; nt < 2; ++nt) {
            int n = n0 + wn * 32 + nt * 16 + lm;
            #pragma unroll
            for (int r = 0; r < 4; ++r) {
                float v = acc[mt][nt][r] * dis[ib + r] * out_scale;
                outT[(size_t)n * NND + ib + r] = (_Float16)v;
            }
        }
    }
}

// ------------- big GEMM: Cp[z][j][n] = sum_{i in z-chunk} Wh[j][i] * Bt[n][i] -------------
// Wh: f16 [8192][8192] (relu'd, transposed attn); Bt: f16 [BN][8192]. No atomics:
// each z writes its own partial slab; k_finalize reduces the 8 slabs.
template <int BN>   // 256 (layer 1) or 128 (layer 2)
__global__ __launch_bounds__(256, 2) void k_mm_big(
    const _Float16* __restrict__ Wh, const _Float16* __restrict__ Bt, float* __restrict__ Cp) {

    constexpr int NT = BN / 32;
    __shared__ _Float16 As[128 * PA];
    __shared__ _Float16 Bs[BN * PA];

    int t = threadIdx.x;
    int j0 = blockIdx.x * 128;
    int i_begin = blockIdx.z * 1024;
    float* C = Cp + (size_t)blockIdx.z * NND * BN;

    int ar = t & 127, akh = t >> 7;          // A staging: row (j), k-half
    int lane = t & 63, w = t >> 6;
    int wm = w & 1, wn = w >> 1;
    int lm = lane & 15, q = lane >> 4;

    floatx4 acc[4][NT];
    #pragma unroll
    for (int a = 0; a < 4; ++a)
        #pragma unroll
        for (int b = 0; b < NT; ++b) acc[a][b] = (floatx4){0.f, 0.f, 0.f, 0.f};

    for (int ks = 0; ks < 32; ++ks) {
        int ib = i_begin + ks * 32;

        const _Float16* asrc = Wh + (size_t)(j0 + ar) * NND + ib + 16 * akh;
        half8 av[2];
        av[0] = *(const half8*)(asrc);
        av[1] = *(const half8*)(asrc + 8);

        half8 bv[(BN == 256) ? 4 : 2];
        if constexpr (BN == 256) {
            const _Float16* src = Bt + (size_t)t * NND + ib;
            #pragma unroll
            for (int c = 0; c < 4; ++c) bv[c] = *(const half8*)(src + 8 * c);
        } else {
            int n = t & 127, kh = t >> 7;
            const _Float16* src = Bt + (size_t)n * NND + ib + 16 * kh;
            #pragma unroll
            for (int c = 0; c < 2; ++c) bv[c] = *(const half8*)(src + 8 * c);
        }

        __syncthreads();
        #pragma unroll
        for (int c = 0; c < 2; ++c) {
            int k = 16 * akh + 8 * c;
            *(half8*)(&As[ar * PA + swzk(ar, k)]) = av[c];
        }
        if constexpr (BN == 256) {
            #pragma unroll
            for (int c = 0; c < 4; ++c)
                *(half8*)(&Bs[t * PA + swzk(t, 8 * c)]) = bv[c];
        } else {
            int n = t & 127, kh = t >> 7;
            #pragma unroll
            for (int c = 0; c < 2; ++c) {
                int k = 16 * kh + 8 * c;
                *(half8*)(&Bs[n * PA + swzk(n, k)]) = bv[c];
            }
        }
        __syncthreads();

        half8 af[4], bf[NT];
        #pragma unroll
        for (int mt = 0; mt < 4; ++mt) {
            int m = wm * 64 + mt * 16 + lm;
            af[mt] = *(const half8*)(&As[m * PA + swzk(m, q * 8)]);
        }
        #pragma unroll
        for (int nt = 0; nt < NT; ++nt) {
            int n = wn * (BN / 2) + nt * 16 + lm;
            bf[nt] = *(const half8*)(&Bs[n * PA + swzk(n, q * 8)]);
        }
        #pragma unroll
        for (int mt = 0; mt < 4; ++mt)
            #pragma unroll
            for (int nt = 0; nt < NT; ++nt)
                acc[mt][nt] = __builtin_amdgcn_mfma_f32_16x16x32_f16(af[mt], bf[nt], acc[mt][nt], 0, 0, 0);
    }

    #pragma unroll
    for (int mt = 0; mt < 4; ++mt) {
        int rb = j0 + wm * 64 + mt * 16 + q * 4;
        #pragma unroll
        for (int nt = 0; nt < NT; ++nt) {
            int col = wn * (BN / 2) + nt * 16 + lm;
            #pragma unroll
            for (int r = 0; r < 4; ++r)
                C[(size_t)(rb + r) * BN + col] = acc[mt][nt][r];
        }
    }
}

// ------------- epilogue: reduce 8 z-partials; out = f16( (dis[j]*S/1024 + bias[n]) [relu] * 64 ) ----
template <int NSH, bool RELU>
__global__ __launch_bounds__(256) void k_finalize(const float* __restrict__ Cp, const float* __restrict__ dis,
                                                  const float* __restrict__ bias, _Float16* __restrict__ out) {
    int idx = blockIdx.x * 256 + threadIdx.x;
    float v = 0.f;
    #pragma unroll
    for (int z = 0; z < 8; ++z) v += Cp[(size_t)z * (NND << NSH) + idx];
    int j = idx >> NSH;
    int n = idx & ((1 << NSH) - 1);
    v = v * (1.f / 1024.f) * dis[j] + bias[n];
    if (RELU) v = fmaxf(v, 0.f);
    out[idx] = (_Float16)(v * 64.f);
}

// ------------- edge scores: 16 lanes per edge, zh rows are 256B -------------
__global__ __launch_bounds__(256) void k_edges(const _Float16* __restrict__ zh, const int* __restrict__ ei,
                                               float* __restrict__ out, int npred) {
    int g = (blockIdx.x * 256 + threadIdx.x) >> 4;
    int l = threadIdx.x & 15;
    if (g >= npred) return;
    int a = ei[g], b = ei[npred + g];
    half8 za = *(const half8*)(zh + (size_t)a * 128 + l * 8);
    half8 zb = *(const half8*)(zh + (size_t)b * 128 + l * 8);
    float s = 0.f;
    #pragma unroll
    for (int e = 0; e < 8; ++e) s += (float)za[e] * (float)zb[e];
    s += __shfl_xor(s, 1);
    s += __shfl_xor(s, 2);
    s += __shfl_xor(s, 4);
    s += __shfl_xor(s, 8);
    if (l == 0) out[g] = s * (1.f / 4096.f);
}

extern "C" void kernel_launch(void* const* d_in, const int* in_sizes, int n_in,
                              void* d_out, int out_size, void* d_ws, size_t ws_size,
                              hipStream_t stream) {
    const int*   nodes = (const int*)d_in[0];
    const float* attn  = (const float*)d_in[1];
    const int*   eidx  = (const int*)d_in[2];
    const float* emb   = (const float*)d_in[3];
    const float* W1    = (const float*)d_in[4];
    const float* b1    = (const float*)d_in[5];
    const float* W2    = (const float*)d_in[6];
    const float* b2    = (const float*)d_in[7];
    float* out = (float*)d_out;
    int npred = in_sizes[2] / 2;

    char* ws = (char*)d_ws;
    float*    deg = (float*)(ws);                         // 32 KB
    float*    dis = (float*)(ws + 0x8000);                // 32 KB
    _Float16* Wh  = (_Float16*)(ws + 0x10000);            // 128 MB f16 [8192][8192] (transposed relu attn)
    float*    C1p = (float*)(ws + 0x8010000);             // 64 MB  fp32 z8 x [8192][256]
    float*    C2p = (float*)(ws + 0xC010000);             // 32 MB  fp32 z8 x [8192][128]
    _Float16* M1p = (_Float16*)(ws + 0xE010000);          // 4 MB   f16 [256][8192]
    _Float16* h   = (_Float16*)(ws + 0xE410000);          // 4 MB   f16 [8192][256]
    _Float16* M2p = (_Float16*)(ws + 0xE810000);          // 2 MB   f16 [128][8192]
    _Float16* zh  = (_Float16*)(ws + 0xEA10000);          // 2 MB   f16 [8192][128]

    hipMemsetAsync(deg, 0, 8192 * sizeof(float), stream);

    k_degT<<<dim3(64, 64), 256, 0, stream>>>(attn, Wh, deg);
    k_dis<<<32, 256, 0, stream>>>(deg, dis);

    // M1p[n][i] = f16(1024 * dis_i * (x@W1)[i,n]);  A staged as 16*x, so out_scale = 64
    k_mm_small<float><<<dim3(64, 4), 256, 0, stream>>>(emb, nodes, W1, 256, M1p, dis, 64.f);
    k_mm_big<256><<<dim3(64, 1, 8), 256, 0, stream>>>(Wh, M1p, C1p);
    // h = relu(dis_j*sum(C1p)/1024 + b1) * 64
    k_finalize<8, true><<<8192, 256, 0, stream>>>(C1p, dis, b1, h);
    // M2p[n][i] = f16(1024 * dis_i * (h_true@W2)[i,n]); h is 64*h_true, so out_scale = 16
    k_mm_small<_Float16><<<dim3(64, 2), 256, 0, stream>>>(h, nullptr, W2, 128, M2p, dis, 16.f);
    k_mm_big<128><<<dim3(64, 1, 8), 256, 0, stream>>>(Wh, M2p, C2p);
    // zh = (dis_j*sum(C2p)/1024 + b2) * 64
    k_finalize<7, false><<<4096, 256, 0, stream>>>(C2p, dis, b2, zh);

    k_edges<<<(npred + 15) / 16, 256, 0, stream>>>(zh, eidx, out, npred);
}